// Round 2
// 667.065 us; speedup vs baseline: 1.0430x; 1.0430x over previous
//
#include <hip/hip_runtime.h>

typedef unsigned short u16;
typedef unsigned int u32;
typedef __attribute__((ext_vector_type(8))) short bf16x8;
typedef __attribute__((ext_vector_type(4))) float f32x4;

#define T_TOK 2048
#define H_DIM 1024
#define E_NUM 8
#define F_DIM 2816
#define BM 128
#define BN1 128
#define BN2 64
#define BK 32
#define LDK 40   // padded LDS row stride in u16: 32 k + 8 pad (80 B rows -> 8 distinct 16B slots)

__device__ __forceinline__ u16 f2bf(float f) {
    u32 b = __float_as_uint(f);
    u32 lsb = (b >> 16) & 1u;
    b += 0x7fffu + lsb;
    return (u16)(b >> 16);
}

// ---------------- Router: logits, softmax, top-2, bucket scatter --------------
__global__ __launch_bounds__(64) void router_kernel(
    const float* __restrict__ x, const float* __restrict__ gw,
    float* __restrict__ logits_out, int* __restrict__ cnt,
    int* __restrict__ tok_list, float* __restrict__ wt_list)
{
    int t = blockIdx.x;
    int lane = threadIdx.x;
    const float* xr = x + (size_t)t * H_DIM;

    float acc[E_NUM];
#pragma unroll
    for (int e = 0; e < E_NUM; e++) acc[e] = 0.f;

    for (int j = 0; j < H_DIM / 64; j++) {
        int idx = j * 64 + lane;
        float xv = xr[idx];
#pragma unroll
        for (int e = 0; e < E_NUM; e++)
            acc[e] += xv * gw[e * H_DIM + idx];
    }
#pragma unroll
    for (int e = 0; e < E_NUM; e++) {
        float v = acc[e];
#pragma unroll
        for (int o = 32; o > 0; o >>= 1) v += __shfl_xor(v, o, 64);
        acc[e] = v;
    }
    if (lane == 0) {
#pragma unroll
        for (int e = 0; e < E_NUM; e++) logits_out[t * E_NUM + e] = acc[e];
        float m = acc[0];
#pragma unroll
        for (int e = 1; e < E_NUM; e++) m = fmaxf(m, acc[e]);
        float p[E_NUM], s = 0.f;
#pragma unroll
        for (int e = 0; e < E_NUM; e++) { p[e] = expf(acc[e] - m); s += p[e]; }
        float inv = 1.f / s;
#pragma unroll
        for (int e = 0; e < E_NUM; e++) p[e] *= inv;
        int i0 = 0;
#pragma unroll
        for (int e = 1; e < E_NUM; e++) if (p[e] > p[i0]) i0 = e;
        int i1 = (i0 == 0) ? 1 : 0;
#pragma unroll
        for (int e = 0; e < E_NUM; e++) if (e != i0 && p[e] > p[i1]) i1 = e;
        float w0 = p[i0], w1 = p[i1];
        float rs = 1.f / (w0 + w1);
        w0 *= rs; w1 *= rs;
        int s0 = atomicAdd(&cnt[i0], 1);
        tok_list[i0 * T_TOK + s0] = t; wt_list[i0 * T_TOK + s0] = w0;
        int s1 = atomicAdd(&cnt[i1], 1);
        tok_list[i1 * T_TOK + s1] = t; wt_list[i1 * T_TOK + s1] = w1;
    }
}

// ---------------- Padded prefix offsets (BM-aligned) --------------------------
__global__ void offsets_kernel(const int* __restrict__ cnt, int* __restrict__ off)
{
    if (threadIdx.x == 0 && blockIdx.x == 0) {
        int s = 0;
        for (int e = 0; e < E_NUM; e++) {
            off[e] = s;
            s += ((cnt[e] + BM - 1) / BM) * BM;
        }
    }
}

// ---------------- GEMM1: act = silu(x*w1) * (x*w3) * wt ----------------------
// 128x128 tile, BK=32, 4 waves (2x2), each wave 64x64 = 4x4 frags of 16x16x32.
// B staged k-major per thread -> packed ds_write_b128 (no bank conflicts).
__global__ __launch_bounds__(256, 2) void gemm1_kernel(
    const float* __restrict__ x, const float* __restrict__ w1,
    const float* __restrict__ w3, const int* __restrict__ cnt,
    const int* __restrict__ off, const int* __restrict__ tok_list,
    const float* __restrict__ wt_list, u16* __restrict__ act)
{
    int e = blockIdx.z;
    int m0 = blockIdx.y * BM;
    int n0 = blockIdx.x * BN1;
    if (m0 >= cnt[e]) return;

    __shared__ __align__(16) u16 As[BM][LDK];
    __shared__ __align__(16) u16 B1[BN1][LDK];
    __shared__ __align__(16) u16 B3[BN1][LDK];
    __shared__ int tok_s[BM];
    __shared__ float wt_s[BM];

    int tid = threadIdx.x;
    if (tid < BM) {
        int tok = tok_list[e * T_TOK + m0 + tid];
        tok_s[tid] = tok;
        wt_s[tid] = (tok >= 0) ? wt_list[e * T_TOK + m0 + tid] : 0.f;
    }
    __syncthreads();

    int wid = tid >> 6, lane = tid & 63, q = lane >> 4, l15 = lane & 15;
    int wr = (wid >> 1) * 64, wc = (wid & 1) * 64;

    const f32x4 zero = {0.f, 0.f, 0.f, 0.f};
    f32x4 accg[4][4], accu[4][4];
#pragma unroll
    for (int i = 0; i < 4; i++)
#pragma unroll
        for (int j = 0; j < 4; j++) { accg[i][j] = zero; accu[i][j] = zero; }

    // A staging: thread owns (row = tid>>1, 16 consecutive k)
    const int arow = tid >> 1, ah = (tid & 1) * 16;
    const int tokA = tok_s[arow];
    // B staging: thread owns one f-column, 16 k values (k-major -> packed write)
    const int bf = tid & 127, bk0 = (tid >> 7) * 16;
    const size_t wb = (size_t)e * H_DIM * F_DIM + n0 + bf;

    for (int k0 = 0; k0 < H_DIM; k0 += BK) {
        // ---- global -> regs (no LDS hazard, overlaps previous compute drain)
        float a16[16];
        if (tokA >= 0) {
            const float4* xr = (const float4*)(x + (size_t)tokA * H_DIM + k0 + ah);
            float4 v0 = xr[0], v1 = xr[1], v2 = xr[2], v3 = xr[3];
            a16[0]=v0.x; a16[1]=v0.y; a16[2]=v0.z;  a16[3]=v0.w;
            a16[4]=v1.x; a16[5]=v1.y; a16[6]=v1.z;  a16[7]=v1.w;
            a16[8]=v2.x; a16[9]=v2.y; a16[10]=v2.z; a16[11]=v2.w;
            a16[12]=v3.x;a16[13]=v3.y;a16[14]=v3.z; a16[15]=v3.w;
        } else {
#pragma unroll
            for (int j = 0; j < 16; j++) a16[j] = 0.f;
        }
        float b1v[16], b3v[16];
        {
            const size_t base = wb + (size_t)(k0 + bk0) * F_DIM;
#pragma unroll
            for (int j = 0; j < 16; j++) {
                b1v[j] = w1[base + (size_t)j * F_DIM];   // lanes: consecutive f -> coalesced
                b3v[j] = w3[base + (size_t)j * F_DIM];
            }
        }
        __syncthreads();
        // ---- convert + packed LDS writes (all ds_write_b128)
        {
            union { uint4 v[2]; u16 u[16]; } pu;
#pragma unroll
            for (int j = 0; j < 16; j++) pu.u[j] = f2bf(a16[j]);
            *(uint4*)&As[arow][ah]     = pu.v[0];
            *(uint4*)&As[arow][ah + 8] = pu.v[1];
#pragma unroll
            for (int j = 0; j < 16; j++) pu.u[j] = f2bf(b1v[j]);
            *(uint4*)&B1[bf][bk0]     = pu.v[0];
            *(uint4*)&B1[bf][bk0 + 8] = pu.v[1];
#pragma unroll
            for (int j = 0; j < 16; j++) pu.u[j] = f2bf(b3v[j]);
            *(uint4*)&B3[bf][bk0]     = pu.v[0];
            *(uint4*)&B3[bf][bk0 + 8] = pu.v[1];
        }
        __syncthreads();

        // ---- fragments + MFMA: 12 ds_read_b128 feed 32 MFMAs per wave
        bf16x8 a[4], f1[4], f3[4];
#pragma unroll
        for (int tm = 0; tm < 4; tm++)
            a[tm] = *(const bf16x8*)&As[wr + tm * 16 + l15][q * 8];
#pragma unroll
        for (int tn = 0; tn < 4; tn++) {
            f1[tn] = *(const bf16x8*)&B1[wc + tn * 16 + l15][q * 8];
            f3[tn] = *(const bf16x8*)&B3[wc + tn * 16 + l15][q * 8];
        }
#pragma unroll
        for (int tm = 0; tm < 4; tm++)
#pragma unroll
            for (int tn = 0; tn < 4; tn++) {
                accg[tm][tn] = __builtin_amdgcn_mfma_f32_16x16x32_bf16(a[tm], f1[tn], accg[tm][tn], 0, 0, 0);
                accu[tm][tn] = __builtin_amdgcn_mfma_f32_16x16x32_bf16(a[tm], f3[tn], accu[tm][tn], 0, 0, 0);
            }
    }

    const int pos0 = off[e] + m0;
#pragma unroll
    for (int tm = 0; tm < 4; tm++) {
        const int row = wr + tm * 16 + q * 4;
#pragma unroll
        for (int r = 0; r < 4; r++) {
            const float wt = wt_s[row + r];
            u16* aptr = act + (size_t)(pos0 + row + r) * F_DIM + n0 + wc + l15;
#pragma unroll
            for (int tn = 0; tn < 4; tn++) {
                float g = accg[tm][tn][r];
                float u = accu[tm][tn][r];
                float sg = g / (1.f + expf(-g));
                aptr[tn * 16] = f2bf(sg * u * wt);
            }
        }
    }
}

// ---------------- GEMM2: out += act * w2 (atomic fp32 scatter into out) ------
// 128x64 tile, BK=32, 4 waves (2x2), each wave 64x32 = 4x2 frags.
__global__ __launch_bounds__(256, 3) void gemm2_kernel(
    const u16* __restrict__ act, const float* __restrict__ w2,
    const int* __restrict__ cnt, const int* __restrict__ off,
    const int* __restrict__ tok_list, float* __restrict__ out)
{
    int e = blockIdx.z;
    int m0 = blockIdx.y * BM;
    int n0 = blockIdx.x * BN2;
    if (m0 >= cnt[e]) return;

    __shared__ __align__(16) u16 As[BM][LDK];
    __shared__ __align__(16) u16 Bt[BN2][LDK];
    __shared__ int tok_s[BM];

    int tid = threadIdx.x;
    if (tid < BM) tok_s[tid] = tok_list[e * T_TOK + m0 + tid];
    __syncthreads();

    int wid = tid >> 6, lane = tid & 63, q = lane >> 4, l15 = lane & 15;
    int wr = (wid >> 1) * 64, wc = (wid & 1) * 32;

    const f32x4 zero = {0.f, 0.f, 0.f, 0.f};
    f32x4 acc[4][2];
#pragma unroll
    for (int i = 0; i < 4; i++)
#pragma unroll
        for (int j = 0; j < 2; j++) acc[i][j] = zero;

    const int arow = tid >> 1, ah = (tid & 1) * 16;
    const size_t abase = (size_t)(off[e] + m0 + arow) * F_DIM + ah;
    const int bh = tid & 63, bk0 = (tid >> 6) * 8;
    const size_t wb = (size_t)e * F_DIM * H_DIM + n0 + bh;

    for (int k0 = 0; k0 < F_DIM; k0 += BK) {
        // act already bf16: pure uint4 copy
        uint4 av0 = *(const uint4*)(act + abase + k0);
        uint4 av1 = *(const uint4*)(act + abase + k0 + 8);
        // w2: k-major scalar loads (coalesced across lanes), packed write
        float bv[8];
        {
            const size_t base = wb + (size_t)(k0 + bk0) * H_DIM;
#pragma unroll
            for (int j = 0; j < 8; j++) bv[j] = w2[base + (size_t)j * H_DIM];
        }
        __syncthreads();
        *(uint4*)&As[arow][ah]     = av0;
        *(uint4*)&As[arow][ah + 8] = av1;
        {
            union { uint4 v; u16 u[8]; } pu;
#pragma unroll
            for (int j = 0; j < 8; j++) pu.u[j] = f2bf(bv[j]);
            *(uint4*)&Bt[bh][bk0] = pu.v;
        }
        __syncthreads();

        bf16x8 a[4], b[2];
#pragma unroll
        for (int tm = 0; tm < 4; tm++)
            a[tm] = *(const bf16x8*)&As[wr + tm * 16 + l15][q * 8];
#pragma unroll
        for (int tn = 0; tn < 2; tn++)
            b[tn] = *(const bf16x8*)&Bt[wc + tn * 16 + l15][q * 8];
#pragma unroll
        for (int tm = 0; tm < 4; tm++)
#pragma unroll
            for (int tn = 0; tn < 2; tn++)
                acc[tm][tn] = __builtin_amdgcn_mfma_f32_16x16x32_bf16(a[tm], b[tn], acc[tm][tn], 0, 0, 0);
    }

#pragma unroll
    for (int tm = 0; tm < 4; tm++) {
        const int row = wr + tm * 16 + q * 4;
#pragma unroll
        for (int r = 0; r < 4; r++) {
            const int tok = tok_s[row + r];
            if (tok >= 0) {
                float* optr = out + (size_t)tok * H_DIM + n0 + wc + l15;
#pragma unroll
                for (int tn = 0; tn < 2; tn++)
                    atomicAdd(&optr[tn * 16], acc[tm][tn][r]);
            }
        }
    }
}

extern "C" void kernel_launch(void* const* d_in, const int* in_sizes, int n_in,
                              void* d_out, int out_size, void* d_ws, size_t ws_size,
                              hipStream_t stream) {
    const float* x  = (const float*)d_in[0];
    const float* gw = (const float*)d_in[1];
    const float* w1 = (const float*)d_in[2];
    const float* w3 = (const float*)d_in[3];
    const float* w2 = (const float*)d_in[4];
    float* out = (float*)d_out;

    char* ws = (char*)d_ws;
    int*   cnt      = (int*)(ws);                    // 32 B used
    int*   off      = (int*)(ws + 64);               // 32 B used
    int*   tok_list = (int*)(ws + 128);              // 64 KiB
    float* wt_list  = (float*)(ws + 128 + 65536);    // 64 KiB
    u16*   act      = (u16*)(ws + 128 + 131072);     // <= ~28.8 MiB (bf16, 128-padded)

    hipMemsetAsync(cnt, 0, 64, stream);
    hipMemsetAsync(tok_list, 0xFF, 65536, stream);
    hipMemsetAsync(out, 0, (size_t)T_TOK * H_DIM * sizeof(float), stream);

    float* logits_out = out + (size_t)T_TOK * H_DIM;
    router_kernel<<<T_TOK, 64, 0, stream>>>(x, gw, logits_out, cnt, tok_list, wt_list);
    offsets_kernel<<<1, 64, 0, stream>>>(cnt, off);
    gemm1_kernel<<<dim3(F_DIM / BN1, T_TOK / BM, E_NUM), 256, 0, stream>>>(
        x, w1, w3, cnt, off, tok_list, wt_list, act);
    gemm2_kernel<<<dim3(H_DIM / BN2, T_TOK / BM, E_NUM), 256, 0, stream>>>(
        act, w2, cnt, off, tok_list, out);
}

// Round 3
// 590.632 us; speedup vs baseline: 1.1779x; 1.1294x over previous
//
#include <hip/hip_runtime.h>

typedef unsigned short u16;
typedef unsigned int u32;
typedef __attribute__((ext_vector_type(8))) short bf16x8;
typedef __attribute__((ext_vector_type(4))) float f32x4;

#define T_TOK 2048
#define H_DIM 1024
#define E_NUM 8
#define F_DIM 2816
#define BM 128
#define BN1 128
#define BN2 64
#define BK1 32
#define BK2 64
#define SPLITF 2
#define FS (F_DIM / SPLITF)          // 1408, 22 iters of 64
#define LDK1 40                      // 80 B rows: 5 16B-slots, odd -> conflict-free b128
#define LDK2 72                      // 144 B rows: 9 16B-slots, odd -> conflict-free b128

__device__ __forceinline__ u16 f2bf(float f) {
    u32 b = __float_as_uint(f);
    u32 lsb = (b >> 16) & 1u;
    b += 0x7fffu + lsb;
    return (u16)(b >> 16);
}

// ---------------- Router: logits, softmax, top-2, bucket scatter --------------
__global__ __launch_bounds__(64) void router_kernel(
    const float* __restrict__ x, const float* __restrict__ gw,
    float* __restrict__ logits_out, int* __restrict__ cnt,
    int* __restrict__ tok_list, float* __restrict__ wt_list)
{
    int t = blockIdx.x;
    int lane = threadIdx.x;
    const float* xr = x + (size_t)t * H_DIM;

    float acc[E_NUM];
#pragma unroll
    for (int e = 0; e < E_NUM; e++) acc[e] = 0.f;

    for (int j = 0; j < H_DIM / 64; j++) {
        int idx = j * 64 + lane;
        float xv = xr[idx];
#pragma unroll
        for (int e = 0; e < E_NUM; e++)
            acc[e] += xv * gw[e * H_DIM + idx];
    }
#pragma unroll
    for (int e = 0; e < E_NUM; e++) {
        float v = acc[e];
#pragma unroll
        for (int o = 32; o > 0; o >>= 1) v += __shfl_xor(v, o, 64);
        acc[e] = v;
    }
    if (lane == 0) {
#pragma unroll
        for (int e = 0; e < E_NUM; e++) logits_out[t * E_NUM + e] = acc[e];
        float m = acc[0];
#pragma unroll
        for (int e = 1; e < E_NUM; e++) m = fmaxf(m, acc[e]);
        float p[E_NUM], s = 0.f;
#pragma unroll
        for (int e = 0; e < E_NUM; e++) { p[e] = expf(acc[e] - m); s += p[e]; }
        float inv = 1.f / s;
#pragma unroll
        for (int e = 0; e < E_NUM; e++) p[e] *= inv;
        int i0 = 0;
#pragma unroll
        for (int e = 1; e < E_NUM; e++) if (p[e] > p[i0]) i0 = e;
        int i1 = (i0 == 0) ? 1 : 0;
#pragma unroll
        for (int e = 0; e < E_NUM; e++) if (e != i0 && p[e] > p[i1]) i1 = e;
        float w0 = p[i0], w1 = p[i1];
        float rs = 1.f / (w0 + w1);
        w0 *= rs; w1 *= rs;
        int s0 = atomicAdd(&cnt[i0], 1);
        tok_list[i0 * T_TOK + s0] = t; wt_list[i0 * T_TOK + s0] = w0;
        int s1 = atomicAdd(&cnt[i1], 1);
        tok_list[i1 * T_TOK + s1] = t; wt_list[i1 * T_TOK + s1] = w1;
    }
}

// ---------------- Padded prefix offsets (BM-aligned) --------------------------
__global__ void offsets_kernel(const int* __restrict__ cnt, int* __restrict__ off)
{
    if (threadIdx.x == 0 && blockIdx.x == 0) {
        int s = 0;
        for (int e = 0; e < E_NUM; e++) {
            off[e] = s;
            s += ((cnt[e] + BM - 1) / BM) * BM;
        }
    }
}

// ---------------- GEMM1: act = silu(x*w1) * (x*w3) * wt ----------------------
// 128x128 tile, BK=32, 4 waves, 4x4 frags/wave, both matmuls share A frags.
// Register prefetch: tile it+1's global loads are issued before tile it's MFMAs.
__global__ __launch_bounds__(256, 2) void gemm1_kernel(
    const float* __restrict__ x, const float* __restrict__ w1,
    const float* __restrict__ w3, const int* __restrict__ cnt,
    const int* __restrict__ off, const int* __restrict__ tok_list,
    const float* __restrict__ wt_list, u16* __restrict__ act)
{
    int e = blockIdx.z;
    int m0 = blockIdx.y * BM;
    int n0 = blockIdx.x * BN1;
    if (m0 >= cnt[e]) return;

    __shared__ __align__(16) u16 As[BM][LDK1];
    __shared__ __align__(16) u16 B1[BN1][LDK1];
    __shared__ __align__(16) u16 B3[BN1][LDK1];
    __shared__ int tok_s[BM];
    __shared__ float wt_s[BM];

    int tid = threadIdx.x;
    if (tid < BM) {
        int tok = tok_list[e * T_TOK + m0 + tid];
        tok_s[tid] = tok;
        wt_s[tid] = (tok >= 0) ? wt_list[e * T_TOK + m0 + tid] : 0.f;
    }
    __syncthreads();

    int wid = tid >> 6, lane = tid & 63, q = lane >> 4, l15 = lane & 15;
    int wr = (wid >> 1) * 64, wc = (wid & 1) * 64;

    const f32x4 zero = {0.f, 0.f, 0.f, 0.f};
    f32x4 accg[4][4], accu[4][4];
#pragma unroll
    for (int i = 0; i < 4; i++)
#pragma unroll
        for (int j = 0; j < 4; j++) { accg[i][j] = zero; accu[i][j] = zero; }

    // A staging: thread owns (row = tid>>1, 16 consecutive k)
    const int arow = tid >> 1, ah = (tid & 1) * 16;
    const int tokA = tok_s[arow];
    const float* xbase = x + (tokA >= 0 ? (size_t)tokA * H_DIM + ah : 0);
    // B staging: thread owns one f-column, 16 k values (k-major -> packed write)
    const int bf = tid & 127, bk0 = (tid >> 7) * 16;
    const size_t wb = (size_t)e * H_DIM * F_DIM + n0 + bf;

    float a16[16], b1v[16], b3v[16];
#pragma unroll
    for (int j = 0; j < 16; j++) a16[j] = 0.f;

    // ---- prologue: load tile 0 into regs
    {
        if (tokA >= 0) {
            const float4* xr = (const float4*)(xbase + 0);
            *(float4*)&a16[0] = xr[0]; *(float4*)&a16[4] = xr[1];
            *(float4*)&a16[8] = xr[2]; *(float4*)&a16[12] = xr[3];
        }
        const size_t base = wb + (size_t)bk0 * F_DIM;
#pragma unroll
        for (int j = 0; j < 16; j++) {
            b1v[j] = w1[base + (size_t)j * F_DIM];
            b3v[j] = w3[base + (size_t)j * F_DIM];
        }
    }

    const int NIT = H_DIM / BK1;
    for (int it = 0; it < NIT; ++it) {
        // ---- convert + packed LDS writes (vmcnt waits for loads issued 1 iter ago)
        {
            union { uint4 v[2]; u16 u[16]; } pu;
#pragma unroll
            for (int j = 0; j < 16; j++) pu.u[j] = f2bf(a16[j]);
            *(uint4*)&As[arow][ah]     = pu.v[0];
            *(uint4*)&As[arow][ah + 8] = pu.v[1];
#pragma unroll
            for (int j = 0; j < 16; j++) pu.u[j] = f2bf(b1v[j]);
            *(uint4*)&B1[bf][bk0]     = pu.v[0];
            *(uint4*)&B1[bf][bk0 + 8] = pu.v[1];
#pragma unroll
            for (int j = 0; j < 16; j++) pu.u[j] = f2bf(b3v[j]);
            *(uint4*)&B3[bf][bk0]     = pu.v[0];
            *(uint4*)&B3[bf][bk0 + 8] = pu.v[1];
        }
        __syncthreads();

        // ---- issue next tile's global loads (in flight during MFMA below)
        if (it + 1 < NIT) {
            const int k0n = (it + 1) * BK1;
            if (tokA >= 0) {
                const float4* xr = (const float4*)(xbase + k0n);
                *(float4*)&a16[0] = xr[0]; *(float4*)&a16[4] = xr[1];
                *(float4*)&a16[8] = xr[2]; *(float4*)&a16[12] = xr[3];
            }
            const size_t base = wb + (size_t)(k0n + bk0) * F_DIM;
#pragma unroll
            for (int j = 0; j < 16; j++) {
                b1v[j] = w1[base + (size_t)j * F_DIM];
                b3v[j] = w3[base + (size_t)j * F_DIM];
            }
        }

        // ---- fragments + MFMA
        bf16x8 a[4], f1[4], f3[4];
#pragma unroll
        for (int tm = 0; tm < 4; tm++)
            a[tm] = *(const bf16x8*)&As[wr + tm * 16 + l15][q * 8];
#pragma unroll
        for (int tn = 0; tn < 4; tn++) {
            f1[tn] = *(const bf16x8*)&B1[wc + tn * 16 + l15][q * 8];
            f3[tn] = *(const bf16x8*)&B3[wc + tn * 16 + l15][q * 8];
        }
#pragma unroll
        for (int tm = 0; tm < 4; tm++)
#pragma unroll
            for (int tn = 0; tn < 4; tn++) {
                accg[tm][tn] = __builtin_amdgcn_mfma_f32_16x16x32_bf16(a[tm], f1[tn], accg[tm][tn], 0, 0, 0);
                accu[tm][tn] = __builtin_amdgcn_mfma_f32_16x16x32_bf16(a[tm], f3[tn], accu[tm][tn], 0, 0, 0);
            }
        __syncthreads();
    }

    const int pos0 = off[e] + m0;
#pragma unroll
    for (int tm = 0; tm < 4; tm++) {
        const int row = wr + tm * 16 + q * 4;
#pragma unroll
        for (int r = 0; r < 4; r++) {
            const float wt = wt_s[row + r];
            u16* aptr = act + (size_t)(pos0 + row + r) * F_DIM + n0 + wc + l15;
#pragma unroll
            for (int tn = 0; tn < 4; tn++) {
                float g = accg[tm][tn][r];
                float u = accu[tm][tn][r];
                float sg = g / (1.f + expf(-g));
                aptr[tn * 16] = f2bf(sg * u * wt);
            }
        }
    }
}

// ---------------- GEMM2: out += act * w2 (atomic fp32 scatter into out) ------
// 128x64 tile, BK=64, split-K over F in SPLITF chunks, 4 waves, 4x2 frags/wave,
// register prefetch pipeline identical to gemm1.
__global__ __launch_bounds__(256, 3) void gemm2_kernel(
    const u16* __restrict__ act, const float* __restrict__ w2,
    const int* __restrict__ cnt, const int* __restrict__ off,
    const int* __restrict__ tok_list, float* __restrict__ out)
{
    int e  = blockIdx.z / SPLITF;
    int ks = blockIdx.z % SPLITF;
    int m0 = blockIdx.y * BM;
    int n0 = blockIdx.x * BN2;
    if (m0 >= cnt[e]) return;

    __shared__ __align__(16) u16 As[BM][LDK2];
    __shared__ __align__(16) u16 Bt[BN2][LDK2];
    __shared__ int tok_s[BM];

    int tid = threadIdx.x;
    if (tid < BM) tok_s[tid] = tok_list[e * T_TOK + m0 + tid];
    __syncthreads();

    int wid = tid >> 6, lane = tid & 63, q = lane >> 4, l15 = lane & 15;
    int wr = (wid >> 1) * 64, wc = (wid & 1) * 32;

    const f32x4 zero = {0.f, 0.f, 0.f, 0.f};
    f32x4 acc[4][2];
#pragma unroll
    for (int i = 0; i < 4; i++)
#pragma unroll
        for (int j = 0; j < 2; j++) acc[i][j] = zero;

    // A staging: thread owns (row = tid>>1, 32 consecutive k) of bf16 act
    const int arow = tid >> 1, ah = (tid & 1) * 32;
    const u16* abase = act + (size_t)(off[e] + m0 + arow) * F_DIM + ah + (size_t)ks * FS;
    // B staging: thread owns h-col bh, 16 k-rows (k-major -> packed writes)
    const int bh = tid & 63, bk0 = (tid >> 6) * 16;
    const float* wbase = w2 + (size_t)e * F_DIM * H_DIM + n0 + bh + (size_t)(ks * FS + bk0) * H_DIM;

    uint4 av[4];
    float bv[16];

    // ---- prologue: load tile 0
    {
#pragma unroll
        for (int j = 0; j < 4; j++) av[j] = *(const uint4*)(abase + j * 8);
#pragma unroll
        for (int j = 0; j < 16; j++) bv[j] = wbase[(size_t)j * H_DIM];
    }

    const int NIT = FS / BK2;
    for (int it = 0; it < NIT; ++it) {
        // ---- LDS writes (vmcnt waits for loads issued 1 iter ago)
#pragma unroll
        for (int j = 0; j < 4; j++) *(uint4*)&As[arow][ah + j * 8] = av[j];
        {
            union { uint4 v[2]; u16 u[16]; } pu;
#pragma unroll
            for (int j = 0; j < 16; j++) pu.u[j] = f2bf(bv[j]);
            *(uint4*)&Bt[bh][bk0]     = pu.v[0];
            *(uint4*)&Bt[bh][bk0 + 8] = pu.v[1];
        }
        __syncthreads();

        // ---- issue next tile's global loads
        if (it + 1 < NIT) {
            const int k0n = (it + 1) * BK2;
#pragma unroll
            for (int j = 0; j < 4; j++) av[j] = *(const uint4*)(abase + k0n + j * 8);
            const float* wnext = wbase + (size_t)k0n * H_DIM;
#pragma unroll
            for (int j = 0; j < 16; j++) bv[j] = wnext[(size_t)j * H_DIM];
        }

        // ---- fragments + MFMA: 2 k-substeps x (4x2) = 16 MFMAs/wave
#pragma unroll
        for (int kk = 0; kk < 2; ++kk) {
            bf16x8 a[4], b[2];
#pragma unroll
            for (int tm = 0; tm < 4; tm++)
                a[tm] = *(const bf16x8*)&As[wr + tm * 16 + l15][kk * 32 + q * 8];
#pragma unroll
            for (int tn = 0; tn < 2; tn++)
                b[tn] = *(const bf16x8*)&Bt[wc + tn * 16 + l15][kk * 32 + q * 8];
#pragma unroll
            for (int tm = 0; tm < 4; tm++)
#pragma unroll
                for (int tn = 0; tn < 2; tn++)
                    acc[tm][tn] = __builtin_amdgcn_mfma_f32_16x16x32_bf16(a[tm], b[tn], acc[tm][tn], 0, 0, 0);
        }
        __syncthreads();
    }

#pragma unroll
    for (int tm = 0; tm < 4; tm++) {
        const int row = wr + tm * 16 + q * 4;
#pragma unroll
        for (int r = 0; r < 4; r++) {
            const int tok = tok_s[row + r];
            if (tok >= 0) {
                float* optr = out + (size_t)tok * H_DIM + n0 + wc + l15;
#pragma unroll
                for (int tn = 0; tn < 2; tn++)
                    atomicAdd(&optr[tn * 16], acc[tm][tn][r]);
            }
        }
    }
}

extern "C" void kernel_launch(void* const* d_in, const int* in_sizes, int n_in,
                              void* d_out, int out_size, void* d_ws, size_t ws_size,
                              hipStream_t stream) {
    const float* x  = (const float*)d_in[0];
    const float* gw = (const float*)d_in[1];
    const float* w1 = (const float*)d_in[2];
    const float* w3 = (const float*)d_in[3];
    const float* w2 = (const float*)d_in[4];
    float* out = (float*)d_out;

    char* ws = (char*)d_ws;
    int*   cnt      = (int*)(ws);                    // 32 B used
    int*   off      = (int*)(ws + 64);               // 32 B used
    int*   tok_list = (int*)(ws + 128);              // 64 KiB
    float* wt_list  = (float*)(ws + 128 + 65536);    // 64 KiB
    u16*   act      = (u16*)(ws + 128 + 131072);     // <= ~28.8 MiB (bf16, 128-padded)

    hipMemsetAsync(cnt, 0, 64, stream);
    hipMemsetAsync(tok_list, 0xFF, 65536, stream);
    hipMemsetAsync(out, 0, (size_t)T_TOK * H_DIM * sizeof(float), stream);

    float* logits_out = out + (size_t)T_TOK * H_DIM;
    router_kernel<<<T_TOK, 64, 0, stream>>>(x, gw, logits_out, cnt, tok_list, wt_list);
    offsets_kernel<<<1, 64, 0, stream>>>(cnt, off);
    gemm1_kernel<<<dim3(F_DIM / BN1, T_TOK / BM, E_NUM), 256, 0, stream>>>(
        x, w1, w3, cnt, off, tok_list, wt_list, act);
    gemm2_kernel<<<dim3(H_DIM / BN2, T_TOK / BM, E_NUM * SPLITF), 256, 0, stream>>>(
        act, w2, cnt, off, tok_list, out);
}

// Round 5
// 589.853 us; speedup vs baseline: 1.1795x; 1.0013x over previous
//
#include <hip/hip_runtime.h>

typedef unsigned short u16;
typedef unsigned int u32;
typedef __attribute__((ext_vector_type(8))) short bf16x8;
typedef __attribute__((ext_vector_type(4))) float f32x4;

#define T_TOK 2048
#define H_DIM 1024
#define E_NUM 8
#define F_DIM 2816
#define BM 128
#define BN1 128
#define BN2 64
#define BK1 32
#define BK2 64
#define LDK1 40   // 80 B rows: start-bank 20*r mod 32 -> conflict-free b128
#define LDK2 72   // 144 B rows: start-bank 36*r mod 32 -> conflict-free b128
#define ROWS_MAX 5120   // max padded slot rows: 4096 + 8*127 = 5112, rounded up

__device__ __forceinline__ u16 f2bf(float f) {
    u32 b = __float_as_uint(f);
    u32 lsb = (b >> 16) & 1u;
    b += 0x7fffu + lsb;
    return (u16)(b >> 16);
}

// ---------------- Router: logits, softmax, top-2, bucket scatter --------------
__global__ __launch_bounds__(64) void router_kernel(
    const float* __restrict__ x, const float* __restrict__ gw,
    float* __restrict__ logits_out, int* __restrict__ cnt,
    int* __restrict__ tok_list, float* __restrict__ wt_list)
{
    int t = blockIdx.x;
    int lane = threadIdx.x;
    const float* xr = x + (size_t)t * H_DIM;

    float acc[E_NUM];
#pragma unroll
    for (int e = 0; e < E_NUM; e++) acc[e] = 0.f;

    for (int j = 0; j < H_DIM / 64; j++) {
        int idx = j * 64 + lane;
        float xv = xr[idx];
#pragma unroll
        for (int e = 0; e < E_NUM; e++)
            acc[e] += xv * gw[e * H_DIM + idx];
    }
#pragma unroll
    for (int e = 0; e < E_NUM; e++) {
        float v = acc[e];
#pragma unroll
        for (int o = 32; o > 0; o >>= 1) v += __shfl_xor(v, o, 64);
        acc[e] = v;
    }
    if (lane == 0) {
#pragma unroll
        for (int e = 0; e < E_NUM; e++) logits_out[t * E_NUM + e] = acc[e];
        float m = acc[0];
#pragma unroll
        for (int e = 1; e < E_NUM; e++) m = fmaxf(m, acc[e]);
        float p[E_NUM], s = 0.f;
#pragma unroll
        for (int e = 0; e < E_NUM; e++) { p[e] = expf(acc[e] - m); s += p[e]; }
        float inv = 1.f / s;
#pragma unroll
        for (int e = 0; e < E_NUM; e++) p[e] *= inv;
        int i0 = 0;
#pragma unroll
        for (int e = 1; e < E_NUM; e++) if (p[e] > p[i0]) i0 = e;
        int i1 = (i0 == 0) ? 1 : 0;
#pragma unroll
        for (int e = 0; e < E_NUM; e++) if (e != i0 && p[e] > p[i1]) i1 = e;
        float w0 = p[i0], w1 = p[i1];
        float rs = 1.f / (w0 + w1);
        w0 *= rs; w1 *= rs;
        int s0 = atomicAdd(&cnt[i0], 1);
        tok_list[i0 * T_TOK + s0] = t; wt_list[i0 * T_TOK + s0] = w0;
        int s1 = atomicAdd(&cnt[i1], 1);
        tok_list[i1 * T_TOK + s1] = t; wt_list[i1 * T_TOK + s1] = w1;
    }
}

// ------- Padded prefix offsets + inverse map token -> its 2 slot positions ----
__global__ __launch_bounds__(256) void offsets_kernel(
    const int* __restrict__ cnt, int* __restrict__ off,
    const int* __restrict__ tok_list, int* __restrict__ inv)
{
    __shared__ int soff[E_NUM];
    __shared__ int tc[T_TOK];
    int tid = threadIdx.x;
    if (tid == 0) {
        int s = 0;
        for (int e = 0; e < E_NUM; e++) {
            soff[e] = s; off[e] = s;
            s += ((cnt[e] + BM - 1) / BM) * BM;
        }
    }
    for (int i = tid; i < T_TOK; i += 256) tc[i] = 0;
    __syncthreads();
    for (int e = 0; e < E_NUM; e++) {
        int c = cnt[e];
        for (int s = tid; s < c; s += 256) {
            int t = tok_list[e * T_TOK + s];
            int sl = atomicAdd(&tc[t], 1);
            inv[t * 2 + sl] = soff[e] + s;
        }
    }
}

// ---------------- GEMM1: act = silu(x*w1) * (x*w3) * wt ----------------------
// 128x128 tile, BK=32, 4 waves, 4x4 frags/wave, both matmuls share A frags.
// Grid (pair=[e|n], m): same-(e,n) m-blocks are gridDim.x=176 apart in
// dispatch order -> same XCD (176 % 8 == 0) -> weight re-reads hit L2.
__global__ __launch_bounds__(256, 2) void gemm1_kernel(
    const float* __restrict__ x, const float* __restrict__ w1,
    const float* __restrict__ w3, const int* __restrict__ cnt,
    const int* __restrict__ off, const int* __restrict__ tok_list,
    const float* __restrict__ wt_list, u16* __restrict__ act)
{
    int pair = blockIdx.x;             // 0..175
    int n_i  = pair % 22;
    int e    = pair / 22;
    int m0 = blockIdx.y * BM;
    int n0 = n_i * BN1;
    if (m0 >= cnt[e]) return;

    __shared__ __align__(16) u16 As[BM][LDK1];
    __shared__ __align__(16) u16 B1[BN1][LDK1];
    __shared__ __align__(16) u16 B3[BN1][LDK1];
    __shared__ int tok_s[BM];
    __shared__ float wt_s[BM];

    int tid = threadIdx.x;
    if (tid < BM) {
        int tok = tok_list[e * T_TOK + m0 + tid];
        tok_s[tid] = tok;
        wt_s[tid] = (tok >= 0) ? wt_list[e * T_TOK + m0 + tid] : 0.f;
    }
    __syncthreads();

    int wid = tid >> 6, lane = tid & 63, q = lane >> 4, l15 = lane & 15;
    int wr = (wid >> 1) * 64, wc = (wid & 1) * 64;

    const f32x4 zero = {0.f, 0.f, 0.f, 0.f};
    f32x4 accg[4][4], accu[4][4];
#pragma unroll
    for (int i = 0; i < 4; i++)
#pragma unroll
        for (int j = 0; j < 4; j++) { accg[i][j] = zero; accu[i][j] = zero; }

    // A staging: thread owns (row = tid>>1, 16 consecutive k)
    const int arow = tid >> 1, ah = (tid & 1) * 16;
    const int tokA = tok_s[arow];
    const float* xbase = x + (tokA >= 0 ? (size_t)tokA * H_DIM + ah : 0);
    // B staging: thread owns one f-column, 16 k values (k-major -> packed write)
    const int bf = tid & 127, bk0 = (tid >> 7) * 16;
    const size_t wb = (size_t)e * H_DIM * F_DIM + n0 + bf;

    float a16[16], b1v[16], b3v[16];
#pragma unroll
    for (int j = 0; j < 16; j++) a16[j] = 0.f;

    // ---- prologue: load tile 0 into regs
    {
        if (tokA >= 0) {
            const float4* xr = (const float4*)(xbase + 0);
            *(float4*)&a16[0] = xr[0]; *(float4*)&a16[4] = xr[1];
            *(float4*)&a16[8] = xr[2]; *(float4*)&a16[12] = xr[3];
        }
        const size_t base = wb + (size_t)bk0 * F_DIM;
#pragma unroll
        for (int j = 0; j < 16; j++) {
            b1v[j] = w1[base + (size_t)j * F_DIM];
            b3v[j] = w3[base + (size_t)j * F_DIM];
        }
    }

    const int NIT = H_DIM / BK1;
    for (int it = 0; it < NIT; ++it) {
        // ---- convert + packed LDS writes (vmcnt waits for loads issued 1 iter ago)
        {
            union { uint4 v[2]; u16 u[16]; } pu;
#pragma unroll
            for (int j = 0; j < 16; j++) pu.u[j] = f2bf(a16[j]);
            *(uint4*)&As[arow][ah]     = pu.v[0];
            *(uint4*)&As[arow][ah + 8] = pu.v[1];
#pragma unroll
            for (int j = 0; j < 16; j++) pu.u[j] = f2bf(b1v[j]);
            *(uint4*)&B1[bf][bk0]     = pu.v[0];
            *(uint4*)&B1[bf][bk0 + 8] = pu.v[1];
#pragma unroll
            for (int j = 0; j < 16; j++) pu.u[j] = f2bf(b3v[j]);
            *(uint4*)&B3[bf][bk0]     = pu.v[0];
            *(uint4*)&B3[bf][bk0 + 8] = pu.v[1];
        }
        __syncthreads();

        // ---- issue next tile's global loads (in flight during MFMA below)
        if (it + 1 < NIT) {
            const int k0n = (it + 1) * BK1;
            if (tokA >= 0) {
                const float4* xr = (const float4*)(xbase + k0n);
                *(float4*)&a16[0] = xr[0]; *(float4*)&a16[4] = xr[1];
                *(float4*)&a16[8] = xr[2]; *(float4*)&a16[12] = xr[3];
            }
            const size_t base = wb + (size_t)(k0n + bk0) * F_DIM;
#pragma unroll
            for (int j = 0; j < 16; j++) {
                b1v[j] = w1[base + (size_t)j * F_DIM];
                b3v[j] = w3[base + (size_t)j * F_DIM];
            }
        }

        // ---- fragments + MFMA
        bf16x8 a[4], f1[4], f3[4];
#pragma unroll
        for (int tm = 0; tm < 4; tm++)
            a[tm] = *(const bf16x8*)&As[wr + tm * 16 + l15][q * 8];
#pragma unroll
        for (int tn = 0; tn < 4; tn++) {
            f1[tn] = *(const bf16x8*)&B1[wc + tn * 16 + l15][q * 8];
            f3[tn] = *(const bf16x8*)&B3[wc + tn * 16 + l15][q * 8];
        }
#pragma unroll
        for (int tm = 0; tm < 4; tm++)
#pragma unroll
            for (int tn = 0; tn < 4; tn++) {
                accg[tm][tn] = __builtin_amdgcn_mfma_f32_16x16x32_bf16(a[tm], f1[tn], accg[tm][tn], 0, 0, 0);
                accu[tm][tn] = __builtin_amdgcn_mfma_f32_16x16x32_bf16(a[tm], f3[tn], accu[tm][tn], 0, 0, 0);
            }
        __syncthreads();
    }

    const int pos0 = off[e] + m0;
#pragma unroll
    for (int tm = 0; tm < 4; tm++) {
        const int row = wr + tm * 16 + q * 4;
#pragma unroll
        for (int r = 0; r < 4; r++) {
            const float wt = wt_s[row + r];
            u16* aptr = act + (size_t)(pos0 + row + r) * F_DIM + n0 + wc + l15;
#pragma unroll
            for (int tn = 0; tn < 4; tn++) {
                float g = accg[tm][tn][r];
                float u = accu[tm][tn][r];
                float sg = g / (1.f + expf(-g));
                aptr[tn * 16] = f2bf(sg * u * wt);
            }
        }
    }
}

// ---------------- GEMM2: rows[ks][pos] = act * w2 (plain stores) --------------
// 128x64 tile, BK=64, split-K over F, 4 waves, 4x2 frags/wave, reg prefetch.
// USE_ROWS: store to rows buffer (no atomics); else atomicAdd into out (fallback).
// Grid (pair=[e|ks|n], m): same-(e,ks,n) m-blocks same XCD (gridDim.x % 8 == 0).
template<int NSPLIT, bool USE_ROWS>
__global__ __launch_bounds__(256, 3) void gemm2_kernel(
    const u16* __restrict__ act, const float* __restrict__ w2,
    const int* __restrict__ cnt, const int* __restrict__ off,
    const int* __restrict__ tok_list, float* __restrict__ rows,
    float* __restrict__ out)
{
    constexpr int FS = F_DIM / NSPLIT;
    int pair = blockIdx.x;            // 0 .. 16*8*NSPLIT-1
    int n_i  = pair & 15;
    int rest = pair >> 4;
    int e  = rest / NSPLIT;
    int ks = rest % NSPLIT;
    int m0 = blockIdx.y * BM;
    int n0 = n_i * BN2;
    if (m0 >= cnt[e]) return;

    __shared__ __align__(16) u16 As[BM][LDK2];
    __shared__ __align__(16) u16 Bt[BN2][LDK2];
    __shared__ int tok_s[BM];

    int tid = threadIdx.x;
    if (tid < BM) tok_s[tid] = tok_list[e * T_TOK + m0 + tid];
    __syncthreads();

    int wid = tid >> 6, lane = tid & 63, q = lane >> 4, l15 = lane & 15;
    int wr = (wid >> 1) * 64, wc = (wid & 1) * 32;

    const f32x4 zero = {0.f, 0.f, 0.f, 0.f};
    f32x4 acc[4][2];
#pragma unroll
    for (int i = 0; i < 4; i++)
#pragma unroll
        for (int j = 0; j < 2; j++) acc[i][j] = zero;

    // A staging: thread owns (row = tid>>1, 32 consecutive k) of bf16 act
    const int arow = tid >> 1, ah = (tid & 1) * 32;
    const u16* abase = act + (size_t)(off[e] + m0 + arow) * F_DIM + ah + (size_t)ks * FS;
    // B staging: thread owns h-col bh, 16 k-rows (k-major -> packed writes)
    const int bh = tid & 63, bk0 = (tid >> 6) * 16;
    const float* wbase = w2 + (size_t)e * F_DIM * H_DIM + n0 + bh + (size_t)(ks * FS + bk0) * H_DIM;

    uint4 av[4];
    float bv[16];

    // ---- prologue: load tile 0
    {
#pragma unroll
        for (int j = 0; j < 4; j++) av[j] = *(const uint4*)(abase + j * 8);
#pragma unroll
        for (int j = 0; j < 16; j++) bv[j] = wbase[(size_t)j * H_DIM];
    }

    const int NIT = FS / BK2;
    for (int it = 0; it < NIT; ++it) {
        // ---- LDS writes (vmcnt waits for loads issued 1 iter ago)
#pragma unroll
        for (int j = 0; j < 4; j++) *(uint4*)&As[arow][ah + j * 8] = av[j];
        {
            union { uint4 v[2]; u16 u[16]; } pu;
#pragma unroll
            for (int j = 0; j < 16; j++) pu.u[j] = f2bf(bv[j]);
            *(uint4*)&Bt[bh][bk0]     = pu.v[0];
            *(uint4*)&Bt[bh][bk0 + 8] = pu.v[1];
        }
        __syncthreads();

        // ---- issue next tile's global loads
        if (it + 1 < NIT) {
            const int k0n = (it + 1) * BK2;
#pragma unroll
            for (int j = 0; j < 4; j++) av[j] = *(const uint4*)(abase + k0n + j * 8);
            const float* wnext = wbase + (size_t)k0n * H_DIM;
#pragma unroll
            for (int j = 0; j < 16; j++) bv[j] = wnext[(size_t)j * H_DIM];
        }

        // ---- fragments + MFMA: 2 k-substeps x (4x2) = 16 MFMAs/wave
#pragma unroll
        for (int kk = 0; kk < 2; ++kk) {
            bf16x8 a[4], b[2];
#pragma unroll
            for (int tm = 0; tm < 4; tm++)
                a[tm] = *(const bf16x8*)&As[wr + tm * 16 + l15][kk * 32 + q * 8];
#pragma unroll
            for (int tn = 0; tn < 2; tn++)
                b[tn] = *(const bf16x8*)&Bt[wc + tn * 16 + l15][kk * 32 + q * 8];
#pragma unroll
            for (int tm = 0; tm < 4; tm++)
#pragma unroll
                for (int tn = 0; tn < 2; tn++)
                    acc[tm][tn] = __builtin_amdgcn_mfma_f32_16x16x32_bf16(a[tm], b[tn], acc[tm][tn], 0, 0, 0);
        }
        __syncthreads();
    }

    if (USE_ROWS) {
        float* rbase = rows + (size_t)ks * ((size_t)ROWS_MAX * H_DIM)
                            + (size_t)(off[e] + m0) * H_DIM;
#pragma unroll
        for (int tm = 0; tm < 4; tm++) {
            const int row = wr + tm * 16 + q * 4;
#pragma unroll
            for (int r = 0; r < 4; r++) {
                float* rp = rbase + (size_t)(row + r) * H_DIM + n0 + wc + l15;
#pragma unroll
                for (int tn = 0; tn < 2; tn++)
                    rp[tn * 16] = acc[tm][tn][r];
            }
        }
    } else {
#pragma unroll
        for (int tm = 0; tm < 4; tm++) {
            const int row = wr + tm * 16 + q * 4;
#pragma unroll
            for (int r = 0; r < 4; r++) {
                const int tok = tok_s[row + r];
                if (tok >= 0) {
                    float* optr = out + (size_t)tok * H_DIM + n0 + wc + l15;
#pragma unroll
                    for (int tn = 0; tn < 2; tn++)
                        atomicAdd(&optr[tn * 16], acc[tm][tn][r]);
                }
            }
        }
    }
}

// ---------------- Combine: out[t] = sum over token's 2 slots (and ks) ---------
template<int NSPLIT>
__global__ __launch_bounds__(256) void combine_kernel(
    const float* __restrict__ rows, const int* __restrict__ inv,
    float* __restrict__ out)
{
    int t = blockIdx.x;
    int h = threadIdx.x * 4;
    int p0 = inv[t * 2], p1 = inv[t * 2 + 1];
    float4 s = {0.f, 0.f, 0.f, 0.f};
#pragma unroll
    for (int ks = 0; ks < NSPLIT; ks++) {
        const float* r = rows + (size_t)ks * ((size_t)ROWS_MAX * H_DIM);
        float4 a = *(const float4*)&r[(size_t)p0 * H_DIM + h];
        float4 b = *(const float4*)&r[(size_t)p1 * H_DIM + h];
        s.x += a.x + b.x; s.y += a.y + b.y; s.z += a.z + b.z; s.w += a.w + b.w;
    }
    *(float4*)&out[(size_t)t * H_DIM + h] = s;
}

extern "C" void kernel_launch(void* const* d_in, const int* in_sizes, int n_in,
                              void* d_out, int out_size, void* d_ws, size_t ws_size,
                              hipStream_t stream) {
    const float* x  = (const float*)d_in[0];
    const float* gw = (const float*)d_in[1];
    const float* w1 = (const float*)d_in[2];
    const float* w3 = (const float*)d_in[3];
    const float* w2 = (const float*)d_in[4];
    float* out = (float*)d_out;

    char* ws = (char*)d_ws;
    int*   cnt      = (int*)(ws);                      // 64 B
    int*   off      = (int*)(ws + 64);                 // 64 B
    int*   tok_list = (int*)(ws + 128);                // 64 KiB
    float* wt_list  = (float*)(ws + 128 + 65536);      // 64 KiB
    int*   inv      = (int*)(ws + 128 + 131072);       // 16 KiB
    u16*   act      = (u16*)(ws + 147584);             // 28.84 MiB
    const size_t act_bytes  = (size_t)ROWS_MAX * F_DIM * sizeof(u16);
    float* rowsbuf  = (float*)(ws + 147584 + act_bytes);
    const size_t rows_one   = (size_t)ROWS_MAX * H_DIM * sizeof(float); // 20.97 MiB
    const size_t base_need  = 147584 + act_bytes;

    hipMemsetAsync(cnt, 0, 64, stream);
    hipMemsetAsync(tok_list, 0xFF, 65536, stream);
    hipMemsetAsync(out, 0, (size_t)T_TOK * H_DIM * sizeof(float), stream);

    float* logits_out = out + (size_t)T_TOK * H_DIM;
    router_kernel<<<T_TOK, 64, 0, stream>>>(x, gw, logits_out, cnt, tok_list, wt_list);
    offsets_kernel<<<1, 256, 0, stream>>>(cnt, off, tok_list, inv);
    gemm1_kernel<<<dim3(22 * E_NUM, T_TOK / BM, 1), 256, 0, stream>>>(
        x, w1, w3, cnt, off, tok_list, wt_list, act);

    if (ws_size >= base_need + 2 * rows_one) {
        gemm2_kernel<2, true><<<dim3(16 * E_NUM * 2, T_TOK / BM, 1), 256, 0, stream>>>(
            act, w2, cnt, off, tok_list, rowsbuf, out);
        combine_kernel<2><<<T_TOK, 256, 0, stream>>>(rowsbuf, inv, out);
    } else if (ws_size >= base_need + rows_one) {
        gemm2_kernel<1, true><<<dim3(16 * E_NUM, T_TOK / BM, 1), 256, 0, stream>>>(
            act, w2, cnt, off, tok_list, rowsbuf, out);
        combine_kernel<1><<<T_TOK, 256, 0, stream>>>(rowsbuf, inv, out);
    } else {
        gemm2_kernel<2, false><<<dim3(16 * E_NUM * 2, T_TOK / BM, 1), 256, 0, stream>>>(
            act, w2, cnt, off, tok_list, nullptr, out);
    }
}